// Round 1
// baseline (228.230 us; speedup 1.0000x reference)
//
#include <hip/hip_runtime.h>

// Blur = separable 4-tap FIR, taps f = [1,3,3,1]/4 = [0.25,0.75,0.75,0.25],
// zero padding: 2 left/top, 1 right/bottom. out[i] = 0.25 x[i-2] + 0.75 x[i-1]
// + 0.75 x[i] + 0.25 x[i+1] per axis. Kernel is palindromic so flip is a no-op.

constexpr int W = 256;
constexpr int H = 256;
constexpr float F0 = 0.25f;
constexpr float F1 = 0.75f;

// Horizontal 4-tap pass on one row. Lane l holds columns [4l, 4l+3] in v.
// Needs x[4l-2], x[4l-1] (prev lane's .z/.w) and x[4l+4] (next lane's .x).
__device__ __forceinline__ float4 hfilt(const float4 v, const int lane) {
    float xl2 = __shfl_up(v.z, 1);    // x[4l-2]
    float xl1 = __shfl_up(v.w, 1);    // x[4l-1]
    float xr  = __shfl_down(v.x, 1);  // x[4l+4]
    if (lane == 0)  { xl2 = 0.0f; xl1 = 0.0f; }  // left zero-pad (2)
    if (lane == 63) { xr = 0.0f; }               // right zero-pad (1)
    float4 h;
    h.x = F0 * xl2 + F1 * xl1 + F1 * v.x + F0 * v.y;
    h.y = F0 * xl1 + F1 * v.x + F1 * v.y + F0 * v.z;
    h.z = F0 * v.x + F1 * v.y + F1 * v.z + F0 * v.w;
    h.w = F0 * v.y + F1 * v.z + F1 * v.w + F0 * xr;
    return h;
}

// One wave per 64-row strip; 4 waves/block = one 256-row (n,c) plane per block.
// Rolling 4-row window of horizontally-filtered rows in registers (A,B,C,D are
// named, statically indexed — avoids scratch spill from runtime-indexed arrays).
__global__ __launch_bounds__(256) void blur_kernel(const float* __restrict__ x,
                                                   float* __restrict__ out) {
    const int plane = blockIdx.x;           // n*C + c
    const int wave  = threadIdx.x >> 6;     // 0..3 -> row strip
    const int lane  = threadIdx.x & 63;
    const float* xp = x + (size_t)plane * (H * W);
    float*       op = out + (size_t)plane * (H * W);
    const int r0  = wave * 64;              // first output row of this strip
    const int col = lane * 4;

    auto loadrow = [&](int i) -> float4 {
        if ((unsigned)i >= (unsigned)H) return make_float4(0.f, 0.f, 0.f, 0.f);
        return *reinterpret_cast<const float4*>(xp + i * W + col);
    };

    // Window: out row io needs h(io-2), h(io-1), h(io), h(io+1).
    float4 A = hfilt(loadrow(r0 - 2), lane);
    float4 B = hfilt(loadrow(r0 - 1), lane);
    float4 C = hfilt(loadrow(r0), lane);

#pragma unroll 4
    for (int t = 0; t < 64; ++t) {
        const int io = r0 + t;
        float4 D = hfilt(loadrow(io + 1), lane);
        float4 o;
        o.x = F0 * (A.x + D.x) + F1 * (B.x + C.x);
        o.y = F0 * (A.y + D.y) + F1 * (B.y + C.y);
        o.z = F0 * (A.z + D.z) + F1 * (B.z + C.z);
        o.w = F0 * (A.w + D.w) + F1 * (B.w + C.w);
        *reinterpret_cast<float4*>(op + io * W + col) = o;
        A = B; B = C; C = D;
    }
}

extern "C" void kernel_launch(void* const* d_in, const int* in_sizes, int n_in,
                              void* d_out, int out_size, void* d_ws, size_t ws_size,
                              hipStream_t stream) {
    const float* x = (const float*)d_in[0];
    float* o = (float*)d_out;
    const int planes = in_sizes[0] / (H * W);  // N*C = 2048
    blur_kernel<<<planes, 256, 0, stream>>>(x, o);
}

// Round 3
// 226.885 us; speedup vs baseline: 1.0059x; 1.0059x over previous
//
#include <hip/hip_runtime.h>

// Blur = separable 4-tap FIR, taps f = [1,3,3,1]/4 = [0.25,0.75,0.75,0.25],
// zero padding: 2 left/top, 1 right/bottom. out[i] = 0.25 x[i-2] + 0.75 x[i-1]
// + 0.75 x[i] + 0.25 x[i+1] per axis. Kernel is palindromic so flip is a no-op.

constexpr int W = 256;
constexpr int H = 256;
constexpr float F0 = 0.25f;
constexpr float F1 = 0.75f;

typedef float f32x4 __attribute__((ext_vector_type(4)));  // clang-native vec for nontemporal builtin

// Horizontal 4-tap pass on one row. Lane l holds columns [4l, 4l+3] in v.
// Needs x[4l-2], x[4l-1] (prev lane's .z/.w) and x[4l+4] (next lane's .x).
__device__ __forceinline__ float4 hfilt(const float4 v, const int lane) {
    float xl2 = __shfl_up(v.z, 1);    // x[4l-2]
    float xl1 = __shfl_up(v.w, 1);    // x[4l-1]
    float xr  = __shfl_down(v.x, 1);  // x[4l+4]
    if (lane == 0)  { xl2 = 0.0f; xl1 = 0.0f; }  // left zero-pad (2)
    if (lane == 63) { xr = 0.0f; }               // right zero-pad (1)
    float4 h;
    h.x = F0 * xl2 + F1 * xl1 + F1 * v.x + F0 * v.y;
    h.y = F0 * xl1 + F1 * v.x + F1 * v.y + F0 * v.z;
    h.z = F0 * v.x + F1 * v.y + F1 * v.z + F0 * v.w;
    h.w = F0 * v.y + F1 * v.z + F1 * v.w + F0 * xr;
    return h;
}

// One wave per 64-row strip; 4 waves/block = one 256-row (n,c) plane per block.
// Rolling 4-row window of horizontally-filtered rows in registers (A,B,C,D are
// named, statically indexed — avoids scratch spill from runtime-indexed arrays).
__global__ __launch_bounds__(256) void blur_kernel(const float* __restrict__ x,
                                                   float* __restrict__ out) {
    const int plane = blockIdx.x;           // n*C + c
    const int wave  = threadIdx.x >> 6;     // 0..3 -> row strip
    const int lane  = threadIdx.x & 63;
    const float* xp = x + (size_t)plane * (H * W);
    float*       op = out + (size_t)plane * (H * W);
    const int r0  = wave * 64;              // first output row of this strip
    const int col = lane * 4;

    auto loadrow = [&](int i) -> float4 {
        if ((unsigned)i >= (unsigned)H) return make_float4(0.f, 0.f, 0.f, 0.f);
        return *reinterpret_cast<const float4*>(xp + i * W + col);
    };

    // Window: out row io needs h(io-2), h(io-1), h(io), h(io+1).
    float4 A = hfilt(loadrow(r0 - 2), lane);
    float4 B = hfilt(loadrow(r0 - 1), lane);
    float4 C = hfilt(loadrow(r0), lane);

#pragma unroll 8
    for (int t = 0; t < 64; ++t) {
        const int io = r0 + t;
        float4 D = hfilt(loadrow(io + 1), lane);
        f32x4 o;
        o.x = F0 * (A.x + D.x) + F1 * (B.x + C.x);
        o.y = F0 * (A.y + D.y) + F1 * (B.y + C.y);
        o.z = F0 * (A.z + D.z) + F1 * (B.z + C.z);
        o.w = F0 * (A.w + D.w) + F1 * (B.w + C.w);
        // Output lines are never re-read: non-temporal store keeps L2 for the
        // input halo rows that neighboring waves re-read.
        __builtin_nontemporal_store(o, reinterpret_cast<f32x4*>(op + io * W + col));
        A = B; B = C; C = D;
    }
}

extern "C" void kernel_launch(void* const* d_in, const int* in_sizes, int n_in,
                              void* d_out, int out_size, void* d_ws, size_t ws_size,
                              hipStream_t stream) {
    const float* x = (const float*)d_in[0];
    float* o = (float*)d_out;
    const int planes = in_sizes[0] / (H * W);  // N*C = 2048
    blur_kernel<<<planes, 256, 0, stream>>>(x, o);
}